// Round 3
// baseline (501.563 us; speedup 1.0000x reference)
//
#include <hip/hip_runtime.h>
#include <hip/hip_bf16.h>
#include <hip/hip_fp16.h>
#include <stdint.h>

typedef __attribute__((ext_vector_type(8))) _Float16 f16x8;
typedef __attribute__((ext_vector_type(4))) float f32x4;

__device__ __forceinline__ void async16(void* lds, const void* g) {
  __builtin_amdgcn_global_load_lds(
      (const __attribute__((address_space(1))) void*)g,
      (__attribute__((address_space(3))) void*)lds, 16, 0, 0);
}

__device__ __forceinline__ uint16_t f2h_u(float f) {
  union { __half h; uint16_t u; } c;
  c.h = __float2half(f);  // v_cvt_f16_f32, RNE
  return c.u;
}
__device__ __forceinline__ float h2f_u(uint16_t u) {
  union { uint16_t u; __half h; } c;
  c.u = u;
  return __half2float(c.h);
}
// split v into fp16 hi + fp16 lo (v ~= hi + lo, residual ~2^-22 |v|)
__device__ __forceinline__ void split16(float v, uint16_t& h, uint16_t& l) {
  __half hh = __float2half(v);
  float r = v - __half2float(hh);
  h = f2h_u(v);
  l = f2h_u(r);
  (void)hh;
}

// ---- x fp32 -> xsplit [8192][2048] fp16: [d]=hi(8x), [1024+d]=lo ----
__global__ __launch_bounds__(256)
void split_x(const float* __restrict__ in, uint16_t* __restrict__ out, int n4) {
  int i = blockIdx.x * 256 + threadIdx.x;
  if (i >= n4) return;
  float4 v = ((const float4*)in)[i];
  int row = (i << 2) >> 10, d = (i << 2) & 1023;
  ushort4 h, l;
  float s;
  s = 8.f * v.x; { __half hh = __float2half(s); h.x = f2h_u(s); l.x = f2h_u(s - __half2float(hh)); }
  s = 8.f * v.y; { __half hh = __float2half(s); h.y = f2h_u(s); l.y = f2h_u(s - __half2float(hh)); }
  s = 8.f * v.z; { __half hh = __float2half(s); h.z = f2h_u(s); l.z = f2h_u(s - __half2float(hh)); }
  s = 8.f * v.w; { __half hh = __float2half(s); h.w = f2h_u(s); l.w = f2h_u(s - __half2float(hh)); }
  *(ushort4*)&out[(size_t)row * 2048 + d] = h;
  *(ushort4*)&out[(size_t)row * 2048 + 1024 + d] = l;
}

// ---- Wqkv[1024][3072] cols<2048 -> Wsp[2048][2048]: [n][d]=hi(128W[d][n]), [n][1024+d]=lo ----
__global__ __launch_bounds__(256)
void wsplit_t(const float* __restrict__ in, uint16_t* __restrict__ out) {
  __shared__ float t[64][65];
  const int tx = threadIdx.x & 63, ty = threadIdx.x >> 6;
  const int r0 = blockIdx.y * 64;  // d
  const int c0 = blockIdx.x * 64;  // n
#pragma unroll
  for (int i = 0; i < 16; ++i)
    t[ty + i * 4][tx] = in[(size_t)(r0 + ty + i * 4) * 3072 + c0 + tx];
  __syncthreads();
#pragma unroll
  for (int i = 0; i < 16; ++i) {
    float v = 128.f * t[tx][ty + i * 4];  // W[r0+tx][c0+ty+i*4]
    uint16_t h, l;
    split16(v, h, l);
    int n = c0 + ty + i * 4, d = r0 + tx;
    out[(size_t)n * 2048 + d] = h;
    out[(size_t)n * 2048 + 1024 + d] = l;
  }
}

// ---- fp32 [R][C] -> fp16 [C][R] transpose (no scale) ----
__global__ __launch_bounds__(256)
void trans_f2h(const float* __restrict__ in, uint16_t* __restrict__ out,
               int ldin, int ldout) {
  __shared__ float t[64][65];
  const int tx = threadIdx.x & 63, ty = threadIdx.x >> 6;
  const int r0 = blockIdx.y * 64, c0 = blockIdx.x * 64;
#pragma unroll
  for (int i = 0; i < 16; ++i)
    t[ty + i * 4][tx] = in[(size_t)(r0 + ty + i * 4) * ldin + c0 + tx];
  __syncthreads();
#pragma unroll
  for (int i = 0; i < 16; ++i)
    out[(size_t)(c0 + ty + i * 4) * ldout + r0 + tx] = f2h_u(t[tx][ty + i * 4]);
}

// ---- 16-bit [R][C] -> [C][R] batched transpose ----
__global__ __launch_bounds__(256)
void trans_16(const uint16_t* __restrict__ in, uint16_t* __restrict__ out,
              int ldin, int ldout, long long strIn, long long strOut) {
  const uint16_t* ip = in + (size_t)blockIdx.z * strIn;
  uint16_t* op = out + (size_t)blockIdx.z * strOut;
  __shared__ uint16_t t[64][65];
  const int tx = threadIdx.x & 63, ty = threadIdx.x >> 6;
  const int r0 = blockIdx.y * 64, c0 = blockIdx.x * 64;
#pragma unroll
  for (int i = 0; i < 16; ++i)
    t[ty + i * 4][tx] = ip[(size_t)(r0 + ty + i * 4) * ldin + c0 + tx];
  __syncthreads();
#pragma unroll
  for (int i = 0; i < 16; ++i)
    op[(size_t)(c0 + ty + i * 4) * ldout + r0 + tx] = t[tx][ty + i * 4];
}

// ---------------- f16 NT GEMM: C = A[M,K]*B[N,K]^T, 128x128 tile, BK=32 ----------------
// SPLIT3: K logical = 3072 over physical [hi|lo] (ld 2048); A thirds {hi,lo,hi}, B {hi,hi,lo}
// EPI: 0 = qk-split writer ; 1 = sps->fp16 ; 2 = v (+bias)->fp16 ; 3 = plain->fp16 ; 4 = +bias->fp32
template <int EPI, bool SPLIT3>
__global__ __launch_bounds__(256)
void gemm_f16(const uint16_t* __restrict__ A, const uint16_t* __restrict__ B,
              void* __restrict__ Cv, void* __restrict__ Cv2,
              const float* __restrict__ bias,
              int K, int lda, int ldb, int ldc,
              long long strA, long long strB, long long strC) {
  __shared__ alignas(16) uint16_t As[128 * 32];
  __shared__ alignas(16) uint16_t Bs[128 * 32];
  const int tid = threadIdx.x;
  const int l = tid & 63;
  const int wv = tid >> 6;
  const int wr = wv >> 1, wc = wv & 1;
  const int l15 = l & 15, l4 = l >> 4;
  const uint16_t* Ag = A + (size_t)blockIdx.z * strA;
  const uint16_t* Bg = B + (size_t)blockIdx.z * strB;
  const int rowBase = blockIdx.x * 128;
  const int colBase = blockIdx.y * 128;

  f32x4 acc[4][4];
#pragma unroll
  for (int m = 0; m < 4; ++m)
#pragma unroll
    for (int n = 0; n < 4; ++n)
      acc[m][n] = (f32x4){0.f, 0.f, 0.f, 0.f};

  const int c0 = tid, c1 = tid + 256;
  const int ar0 = c0 >> 2, ak0 = (c0 & 3) * 8;
  const int ar1 = c1 >> 2, ak1 = (c1 & 3) * 8;
  const size_t ra0 = (size_t)(rowBase + ar0) * lda + ak0;
  const size_t ra1 = (size_t)(rowBase + ar1) * lda + ak1;
  const size_t rb0 = (size_t)(colBase + ar0) * ldb + ak0;
  const size_t rb1 = (size_t)(colBase + ar1) * ldb + ak1;

  const int nK = K >> 5;
  for (int kt = 0; kt < nK; ++kt) {
    int kcol, aoff, boff;
    if (SPLIT3) {
      const int third = kt >> 5;
      kcol = (kt & 31) * 32;
      aoff = (third == 1) ? 1024 : 0;
      boff = (third == 2) ? 1024 : 0;
    } else {
      kcol = kt * 32;
      aoff = 0;
      boff = 0;
    }
    async16(&As[c0 * 8], Ag + ra0 + aoff + kcol);
    async16(&As[c1 * 8], Ag + ra1 + aoff + kcol);
    async16(&Bs[c0 * 8], Bg + rb0 + boff + kcol);
    async16(&Bs[c1 * 8], Bg + rb1 + boff + kcol);
    __syncthreads();  // drains vmcnt
    f16x8 af[4], bfr[4];
#pragma unroll
    for (int m = 0; m < 4; ++m)
      af[m] = *(const f16x8*)&As[(wr * 64 + m * 16 + l15) * 32 + l4 * 8];
#pragma unroll
    for (int n = 0; n < 4; ++n)
      bfr[n] = *(const f16x8*)&Bs[(wc * 64 + n * 16 + l15) * 32 + l4 * 8];
#pragma unroll
    for (int m = 0; m < 4; ++m)
#pragma unroll
      for (int n = 0; n < 4; ++n)
        acc[m][n] = __builtin_amdgcn_mfma_f32_16x16x32_f16(af[m], bfr[n], acc[m][n], 0, 0, 0);
    __syncthreads();
  }

  const int orow = rowBase + wr * 64 + l4 * 4;
  const int ocol = colBase + wc * 64 + l15;
  if (EPI == 0) {
    // acc = (8x)@(128W) = 1024*(x@W); s = acc/1024 + bias; store hi/lo of 8s
    uint16_t* qd = (uint16_t*)Cv;
    uint16_t* kd = (uint16_t*)Cv2;
#pragma unroll
    for (int n = 0; n < 4; ++n) {
      const int gcol = ocol + n * 16;
      const float bv = bias[gcol];
      uint16_t* base = (gcol < 1024 ? qd : kd) + (gcol & 1023);
#pragma unroll
      for (int m = 0; m < 4; ++m)
#pragma unroll
        for (int j = 0; j < 4; ++j) {
          const int grow = orow + m * 16 + j;
          float s = acc[m][n][j] * (1.0f / 1024.0f) + bv;
          float s8 = 8.0f * s;
          __half hh = __float2half(s8);
          float r = s8 - __half2float(hh);
          const int b = grow >> 11, t = grow & 2047;
          uint16_t* dst = base + (size_t)b * 4194304 + (size_t)t * 2048;
          dst[0] = f2h_u(s8);
          dst[1024] = f2h_u(r);
        }
    }
  } else if (EPI == 1) {
    // acc = (8q)@(8k) = 64*(q@k); xs = acc/64*0.125 = acc/512
    uint16_t* C = (uint16_t*)Cv + (size_t)blockIdx.z * strC;
#pragma unroll
    for (int n = 0; n < 4; ++n)
#pragma unroll
      for (int m = 0; m < 4; ++m)
#pragma unroll
        for (int j = 0; j < 4; ++j) {
          float xs = acc[m][n][j] * (1.0f / 512.0f);
          // sig(x)>0.95<=>x>ln19 ; >0.85<=>x>ln(17/3) ; <0.1<=>x<-ln9 ; <0.25<=>x<-ln3
          float mult = (xs > 2.94443897916644f) ? 2.0f
                     : (xs > 1.73460105538811f) ? 1.5f
                     : (xs < -2.19722457733622f) ? 0.1f
                     : (xs < -1.09861228866811f) ? 0.3f
                                                 : 1.0f;
          C[(size_t)(orow + m * 16 + j) * ldc + ocol + n * 16] = f2h_u(xs * mult);
        }
  } else if (EPI == 2) {
    // acc = (8x)@Wv = 8*v_pre; s = acc/8 + bias
    uint16_t* C = (uint16_t*)Cv;
#pragma unroll
    for (int n = 0; n < 4; ++n) {
      const float bv = bias[ocol + n * 16];
#pragma unroll
      for (int m = 0; m < 4; ++m)
#pragma unroll
        for (int j = 0; j < 4; ++j)
          C[(size_t)(orow + m * 16 + j) * ldc + ocol + n * 16] =
              f2h_u(acc[m][n][j] * 0.125f + bv);
    }
  } else if (EPI == 3) {
    uint16_t* C = (uint16_t*)Cv + (size_t)blockIdx.z * strC;
#pragma unroll
    for (int n = 0; n < 4; ++n)
#pragma unroll
      for (int m = 0; m < 4; ++m)
#pragma unroll
        for (int j = 0; j < 4; ++j)
          C[(size_t)(orow + m * 16 + j) * ldc + ocol + n * 16] = f2h_u(acc[m][n][j]);
  } else {
    float* C = (float*)Cv;
#pragma unroll
    for (int n = 0; n < 4; ++n) {
      const float bv = bias[ocol + n * 16];
#pragma unroll
      for (int m = 0; m < 4; ++m)
#pragma unroll
        for (int j = 0; j < 4; ++j)
          C[(size_t)(orow + m * 16 + j) * ldc + ocol + n * 16] = acc[m][n][j] + bv;
    }
  }
}

// ---- row softmax over fp16 logits -> fp16 probs, in place ----
__global__ __launch_bounds__(256)
void softmax_rows(uint16_t* __restrict__ P) {
  const size_t row = blockIdx.x;
  uint16_t* p = P + row * 2048;
  const int tid = threadIdx.x;
  uint4 raw = *(const uint4*)(p + tid * 8);
  uint32_t w[4] = {raw.x, raw.y, raw.z, raw.w};
  float v[8];
#pragma unroll
  for (int q = 0; q < 4; ++q) {
    __half2 h = *(__half2*)&w[q];
    float2 f = __half22float2(h);
    v[2 * q] = f.x;
    v[2 * q + 1] = f.y;
  }
  float mx = v[0];
#pragma unroll
  for (int j = 1; j < 8; ++j) mx = fmaxf(mx, v[j]);
#pragma unroll
  for (int o = 32; o > 0; o >>= 1) mx = fmaxf(mx, __shfl_xor(mx, o));
  __shared__ float redm[4], reds[4];
  if ((tid & 63) == 0) redm[tid >> 6] = mx;
  __syncthreads();
  mx = fmaxf(fmaxf(redm[0], redm[1]), fmaxf(redm[2], redm[3]));
  float e[8];
  float se = 0.f;
#pragma unroll
  for (int j = 0; j < 8; ++j) { e[j] = __expf(v[j] - mx); se += e[j]; }
#pragma unroll
  for (int o = 32; o > 0; o >>= 1) se += __shfl_xor(se, o);
  if ((tid & 63) == 0) reds[tid >> 6] = se;
  __syncthreads();
  se = (reds[0] + reds[1]) + (reds[2] + reds[3]);
  const float inv = 1.0f / se;
  uint32_t wo[4];
#pragma unroll
  for (int q = 0; q < 4; ++q) {
    uint16_t a = f2h_u(e[2 * q] * inv);
    uint16_t b = f2h_u(e[2 * q + 1] * inv);
    wo[q] = (uint32_t)a | ((uint32_t)b << 16);
  }
  uint4 ov;
  ov.x = wo[0]; ov.y = wo[1]; ov.z = wo[2]; ov.w = wo[3];
  *(uint4*)(p + tid * 8) = ov;
}

extern "C" void kernel_launch(void* const* d_in, const int* in_sizes, int n_in,
                              void* d_out, int out_size, void* d_ws, size_t ws_size,
                              hipStream_t stream) {
  const float* x     = (const float*)d_in[0];
  const float* Wqkv  = (const float*)d_in[1];
  const float* bqkv  = (const float*)d_in[2];
  const float* Wproj = (const float*)d_in[3];
  const float* bproj = (const float*)d_in[4];
  float* out = (float*)d_out;

  char* ws = (char*)d_ws;
  size_t off = 0;
  auto alloc = [&](size_t bytes) -> void* {
    void* p = ws + off;
    off += (bytes + 255) & ~(size_t)255;
    return p;
  };
  uint16_t* xsplit = (uint16_t*)alloc(8192ULL * 2048 * 2);   // [8192][hi|lo] of 8x
  uint16_t* Wsp    = (uint16_t*)alloc(2048ULL * 2048 * 2);   // [n][hi|lo] of 128*Wqk
  uint16_t* WvT    = (uint16_t*)alloc(1024ULL * 1024 * 2);   // Wv^T fp16
  uint16_t* WpT    = (uint16_t*)alloc(1024ULL * 1024 * 2);   // Wproj^T fp16
  uint16_t* qsp    = (uint16_t*)alloc(4ULL * 2048 * 2048 * 2);  // q splits (8q hi|lo)
  uint16_t* ksp    = (uint16_t*)alloc(4ULL * 2048 * 2048 * 2);  // k splits
  uint16_t* vtmp   = (uint16_t*)alloc(8192ULL * 1024 * 2);   // v fp16 [b t][d]
  uint16_t* vT     = (uint16_t*)alloc(4ULL * 1024 * 2048 * 2);  // v^T fp16 [b][d][t]
  uint16_t* Pm     = (uint16_t*)alloc(4ULL * 2048 * 2048 * 2);  // logits/probs fp16
  uint16_t* ao     = xsplit;  // attn-out fp16 reuses xsplit (dead after v GEMM)

  // 1. x -> scaled fp16 split
  split_x<<<8192, 256, 0, stream>>>(x, xsplit, 2097152);
  // 2. weight preps
  wsplit_t<<<dim3(32, 16), 256, 0, stream>>>(Wqkv, Wsp);
  trans_f2h<<<dim3(16, 16), 256, 0, stream>>>(Wqkv + 2048, WvT, 3072, 1024);
  trans_f2h<<<dim3(16, 16), 256, 0, stream>>>(Wproj, WpT, 1024, 1024);
  // 3. q,k = x@Wqk + b (split3, K=3072) -> split fp16 q,k
  gemm_f16<0, true><<<dim3(64, 16, 1), 256, 0, stream>>>(
      xsplit, Wsp, qsp, ksp, bqkv, 3072, 2048, 2048, 0, 0, 0, 0);
  // 4. v = x@Wv + b (plain, K=1024)
  gemm_f16<2, false><<<dim3(64, 8, 1), 256, 0, stream>>>(
      xsplit, WvT, vtmp, nullptr, bqkv + 2048, 1024, 2048, 1024, 1024, 0, 0, 0);
  // 5. v -> vT per batch
  trans_16<<<dim3(16, 32, 4), 256, 0, stream>>>(vtmp, vT, 1024, 2048, 2097152LL, 2097152LL);
  // 6. logits = sps(q@k^T * scale) (split3, K=3072) -> fp16
  gemm_f16<1, true><<<dim3(16, 16, 4), 256, 0, stream>>>(
      qsp, ksp, Pm, nullptr, nullptr, 3072, 2048, 2048, 2048,
      4194304LL, 4194304LL, 4194304LL);
  // 7. softmax rows in place
  softmax_rows<<<8192, 256, 0, stream>>>(Pm);
  // 8. attn_out = P@V (K=2048)
  gemm_f16<3, false><<<dim3(16, 8, 4), 256, 0, stream>>>(
      Pm, vT, ao, nullptr, nullptr, 2048, 2048, 2048, 1024,
      4194304LL, 2097152LL, 2097152LL);
  // 9. out = ao@Wproj + b -> fp32
  gemm_f16<4, false><<<dim3(64, 8, 1), 256, 0, stream>>>(
      ao, WpT, out, nullptr, bproj, 1024, 1024, 1024, 1024, 0, 0, 0);
}

// Round 4
// 424.314 us; speedup vs baseline: 1.1821x; 1.1821x over previous
//
#include <hip/hip_runtime.h>
#include <hip/hip_bf16.h>
#include <hip/hip_fp16.h>
#include <stdint.h>

typedef __attribute__((ext_vector_type(8))) _Float16 f16x8;
typedef __attribute__((ext_vector_type(4))) float f32x4;

__device__ __forceinline__ void async16(void* lds, const void* g) {
  __builtin_amdgcn_global_load_lds(
      (const __attribute__((address_space(1))) void*)g,
      (__attribute__((address_space(3))) void*)lds, 16, 0, 0);
}

__device__ __forceinline__ uint16_t f2h_u(float f) {
  union { __half h; uint16_t u; } c;
  c.h = __float2half(f);  // v_cvt_f16_f32, RNE
  return c.u;
}
// split v into fp16 hi + fp16 lo (v ~= hi + lo, residual ~2^-22 |v|)
__device__ __forceinline__ void split16(float v, uint16_t& h, uint16_t& l) {
  __half hh = __float2half(v);
  float r = v - __half2float(hh);
  h = f2h_u(v);
  l = f2h_u(r);
  (void)hh;
}

// ---- x fp32 -> xsplit [8192][2048] fp16: [d]=hi(8x), [1024+d]=lo ----
__global__ __launch_bounds__(256)
void split_x(const float* __restrict__ in, uint16_t* __restrict__ out, int n4) {
  int i = blockIdx.x * 256 + threadIdx.x;
  if (i >= n4) return;
  float4 v = ((const float4*)in)[i];
  int row = (i << 2) >> 10, d = (i << 2) & 1023;
  ushort4 h, l;
  float s;
  s = 8.f * v.x; { __half hh = __float2half(s); h.x = f2h_u(s); l.x = f2h_u(s - __half2float(hh)); }
  s = 8.f * v.y; { __half hh = __float2half(s); h.y = f2h_u(s); l.y = f2h_u(s - __half2float(hh)); }
  s = 8.f * v.z; { __half hh = __float2half(s); h.z = f2h_u(s); l.z = f2h_u(s - __half2float(hh)); }
  s = 8.f * v.w; { __half hh = __float2half(s); h.w = f2h_u(s); l.w = f2h_u(s - __half2float(hh)); }
  *(ushort4*)&out[(size_t)row * 2048 + d] = h;
  *(ushort4*)&out[(size_t)row * 2048 + 1024 + d] = l;
}

// ---- Wqkv[1024][3072] cols<2048 -> Wsp[2048][2048]: [n][d]=hi(128W[d][n]), [n][1024+d]=lo ----
__global__ __launch_bounds__(256)
void wsplit_t(const float* __restrict__ in, uint16_t* __restrict__ out) {
  __shared__ float t[64][65];
  const int tx = threadIdx.x & 63, ty = threadIdx.x >> 6;
  const int r0 = blockIdx.y * 64;  // d
  const int c0 = blockIdx.x * 64;  // n
#pragma unroll
  for (int i = 0; i < 16; ++i)
    t[ty + i * 4][tx] = in[(size_t)(r0 + ty + i * 4) * 3072 + c0 + tx];
  __syncthreads();
#pragma unroll
  for (int i = 0; i < 16; ++i) {
    float v = 128.f * t[tx][ty + i * 4];  // W[r0+tx][c0+ty+i*4]
    uint16_t h, l;
    split16(v, h, l);
    int n = c0 + ty + i * 4, d = r0 + tx;
    out[(size_t)n * 2048 + d] = h;
    out[(size_t)n * 2048 + 1024 + d] = l;
  }
}

// ---- fp32 [R][C] -> fp16 [C][R] transpose (no scale) ----
__global__ __launch_bounds__(256)
void trans_f2h(const float* __restrict__ in, uint16_t* __restrict__ out,
               int ldin, int ldout) {
  __shared__ float t[64][65];
  const int tx = threadIdx.x & 63, ty = threadIdx.x >> 6;
  const int r0 = blockIdx.y * 64, c0 = blockIdx.x * 64;
#pragma unroll
  for (int i = 0; i < 16; ++i)
    t[ty + i * 4][tx] = in[(size_t)(r0 + ty + i * 4) * ldin + c0 + tx];
  __syncthreads();
#pragma unroll
  for (int i = 0; i < 16; ++i)
    out[(size_t)(c0 + ty + i * 4) * ldout + r0 + tx] = f2h_u(t[tx][ty + i * 4]);
}

// ---- 16-bit [R][C] -> [C][R] batched transpose ----
__global__ __launch_bounds__(256)
void trans_16(const uint16_t* __restrict__ in, uint16_t* __restrict__ out,
              int ldin, int ldout, long long strIn, long long strOut) {
  const uint16_t* ip = in + (size_t)blockIdx.z * strIn;
  uint16_t* op = out + (size_t)blockIdx.z * strOut;
  __shared__ uint16_t t[64][65];
  const int tx = threadIdx.x & 63, ty = threadIdx.x >> 6;
  const int r0 = blockIdx.y * 64, c0 = blockIdx.x * 64;
#pragma unroll
  for (int i = 0; i < 16; ++i)
    t[ty + i * 4][tx] = ip[(size_t)(r0 + ty + i * 4) * ldin + c0 + tx];
  __syncthreads();
#pragma unroll
  for (int i = 0; i < 16; ++i)
    op[(size_t)(c0 + ty + i * 4) * ldout + r0 + tx] = t[tx][ty + i * 4];
}

// ================= big-K split3 GEMM: 256x128 tile, BK=64, ring-3 LDS, 8 waves =================
// C = A[M,3072-split]*B[N,3072-split]^T ; A thirds {hi,lo,hi}, B thirds {hi,hi,lo} (ld 2048)
// EPI: 0 = qk-split writer ; 1 = sps->fp16
template <int EPI>
__global__ __launch_bounds__(512, 2)
void gemm256(const uint16_t* __restrict__ A, const uint16_t* __restrict__ B,
             void* __restrict__ Cv, void* __restrict__ Cv2,
             const float* __restrict__ bias,
             int lda, int ldb, int ldc,
             long long strA, long long strB, long long strC) {
  extern __shared__ uint16_t lds_u16[];  // 3 slots x (A 256x64 + B 128x64) fp16 = 144 KB

  // bijective XCD swizzle on flat block id (nwg % 8 == 0)
  const int gx = gridDim.x, gy = gridDim.y;
  const int nwg = gx * gy * gridDim.z;
  const int fid = blockIdx.x + gx * (blockIdx.y + gy * blockIdx.z);
  const int fs = (fid & 7) * (nwg >> 3) + (fid >> 3);
  const int bx = fs % gx;
  const int by = (fs / gx) % gy;
  const int bz = fs / (gx * gy);

  const int tid = threadIdx.x;
  const int l = tid & 63;
  const int w = tid >> 6;
  const int wm = w >> 1, wn = w & 1;
  const int l15 = l & 15, l4 = l >> 4;
  const int rowBase = bx * 256, colBase = by * 128;
  const uint16_t* Ag = A + (size_t)bz * strA;
  const uint16_t* Bg = B + (size_t)bz * strB;

  // staging source pointers: linear LDS dest chunk c <- global chunk c^((c>>3)&7)
  const uint16_t* pA[4];
  const uint16_t* pB[2];
#pragma unroll
  for (int u = 0; u < 4; ++u) {
    int c = tid + (u << 9);
    int cs = c ^ ((c >> 3) & 7);
    pA[u] = Ag + (size_t)(rowBase + (cs >> 3)) * lda + (cs & 7) * 8;
  }
#pragma unroll
  for (int u = 0; u < 2; ++u) {
    int c = tid + (u << 9);
    int cs = c ^ ((c >> 3) & 7);
    pB[u] = Bg + (size_t)(colBase + (cs >> 3)) * ldb + (cs & 7) * 8;
  }

  f32x4 acc[4][4];
#pragma unroll
  for (int m = 0; m < 4; ++m)
#pragma unroll
    for (int n = 0; n < 4; ++n)
      acc[m][n] = (f32x4){0.f, 0.f, 0.f, 0.f};

  // stage K-tile t2 (of 48) into slot t2%3: 4 A-chunks + 2 B-chunks per thread
#define STAGE(t2)                                                              \
  {                                                                            \
    const int third_ = (t2) >> 4;                                              \
    const int kbA_ = (((t2) & 15) << 6) + ((third_ == 1) ? 1024 : 0);          \
    const int kbB_ = (((t2) & 15) << 6) + ((third_ == 2) ? 1024 : 0);          \
    uint16_t* dA_ = lds_u16 + ((t2) % 3) * 24576;                              \
    uint16_t* dB_ = dA_ + 16384;                                               \
    _Pragma("unroll") for (int u = 0; u < 4; ++u)                              \
        async16(&dA_[(size_t)(tid + (u << 9)) * 8], pA[u] + kbA_);             \
    _Pragma("unroll") for (int u = 0; u < 2; ++u)                              \
        async16(&dB_[(size_t)(tid + (u << 9)) * 8], pB[u] + kbB_);             \
  }

  // prologue: tiles 0 and 1 in flight; wait for tile 0 (6 loads of tile 1 remain)
  STAGE(0)
  STAGE(1)
  asm volatile("s_waitcnt vmcnt(6)" ::: "memory");
  __builtin_amdgcn_s_barrier();

  for (int t = 0; t < 48; ++t) {
    if (t + 2 < 48) STAGE(t + 2)
    const uint16_t* As = lds_u16 + (t % 3) * 24576;
    const uint16_t* Bs = As + 16384;
#pragma unroll
    for (int ks = 0; ks < 2; ++ks) {
      f16x8 af[4], bf[4];
#pragma unroll
      for (int m = 0; m < 4; ++m) {
        const int r = wm * 64 + m * 16 + l15;
        const int byt = r * 128 + ((ks * 64 + l4 * 16) ^ ((r & 7) << 4));
        af[m] = *(const f16x8*)((const char*)As + byt);
      }
#pragma unroll
      for (int n = 0; n < 4; ++n) {
        const int r = wn * 64 + n * 16 + l15;
        const int byt = r * 128 + ((ks * 64 + l4 * 16) ^ ((r & 7) << 4));
        bf[n] = *(const f16x8*)((const char*)Bs + byt);
      }
      __builtin_amdgcn_s_setprio(1);
#pragma unroll
      for (int m = 0; m < 4; ++m)
#pragma unroll
        for (int n = 0; n < 4; ++n)
          acc[m][n] = __builtin_amdgcn_mfma_f32_16x16x32_f16(af[m], bf[n], acc[m][n], 0, 0, 0);
      __builtin_amdgcn_s_setprio(0);
    }
    if (t + 1 < 48) {
      if (t + 2 < 48) {
        asm volatile("s_waitcnt vmcnt(6)" ::: "memory");  // tile t+1 landed; t+2 in flight
      } else {
        asm volatile("s_waitcnt vmcnt(0)" ::: "memory");
      }
      __builtin_amdgcn_s_barrier();
    }
  }
#undef STAGE

  const int orow0 = rowBase + wm * 64 + l4 * 4;
  const int ocol0 = colBase + wn * 64 + l15;
  if (EPI == 0) {
    // acc = (8x)@(128W) = 1024*(x@W); s8 = acc/128 + 8*bias; store fp16 hi/lo of 8s
    uint16_t* qd = (uint16_t*)Cv;
    uint16_t* kd = (uint16_t*)Cv2;
#pragma unroll
    for (int n = 0; n < 4; ++n) {
      const int gcol = ocol0 + n * 16;
      const float bv8 = 8.0f * bias[gcol];
      uint16_t* base = (gcol < 1024 ? qd : kd) + (gcol & 1023);
#pragma unroll
      for (int m = 0; m < 4; ++m)
#pragma unroll
        for (int j = 0; j < 4; ++j) {
          const int grow = orow0 + m * 16 + j;
          float s8 = acc[m][n][j] * (1.0f / 128.0f) + bv8;
          __half hh = __float2half(s8);
          float r = s8 - __half2float(hh);
          uint16_t* dst = base + (size_t)(grow >> 11) * 4194304 + (size_t)(grow & 2047) * 2048;
          dst[0] = f2h_u(s8);
          dst[1024] = f2h_u(r);
        }
    }
  } else {
    // acc = (8q)@(8k) = 64*(q@k); xs = acc/512 ; sps bands in logit space
    uint16_t* C = (uint16_t*)Cv + (size_t)bz * strC;
#pragma unroll
    for (int n = 0; n < 4; ++n)
#pragma unroll
      for (int m = 0; m < 4; ++m)
#pragma unroll
        for (int j = 0; j < 4; ++j) {
          float xs = acc[m][n][j] * (1.0f / 512.0f);
          float mult = (xs > 2.94443897916644f) ? 2.0f
                     : (xs > 1.73460105538811f) ? 1.5f
                     : (xs < -2.19722457733622f) ? 0.1f
                     : (xs < -1.09861228866811f) ? 0.3f
                                                 : 1.0f;
          C[(size_t)(orow0 + m * 16 + j) * ldc + ocol0 + n * 16] = f2h_u(xs * mult);
        }
  }
}

// ---------------- f16 NT GEMM (small ones): 128x128 tile, BK=32 ----------------
// EPI: 2 = v (+bias)->fp16 ; 3 = plain->fp16 ; 4 = +bias->fp32
template <int EPI>
__global__ __launch_bounds__(256)
void gemm_f16(const uint16_t* __restrict__ A, const uint16_t* __restrict__ B,
              void* __restrict__ Cv, const float* __restrict__ bias,
              int K, int lda, int ldb, int ldc,
              long long strA, long long strB, long long strC) {
  __shared__ alignas(16) uint16_t As[128 * 32];
  __shared__ alignas(16) uint16_t Bs[128 * 32];
  const int tid = threadIdx.x;
  const int l = tid & 63;
  const int wv = tid >> 6;
  const int wr = wv >> 1, wc = wv & 1;
  const int l15 = l & 15, l4 = l >> 4;
  const uint16_t* Ag = A + (size_t)blockIdx.z * strA;
  const uint16_t* Bg = B + (size_t)blockIdx.z * strB;
  const int rowBase = blockIdx.x * 128;
  const int colBase = blockIdx.y * 128;

  f32x4 acc[4][4];
#pragma unroll
  for (int m = 0; m < 4; ++m)
#pragma unroll
    for (int n = 0; n < 4; ++n)
      acc[m][n] = (f32x4){0.f, 0.f, 0.f, 0.f};

  const int c0 = tid, c1 = tid + 256;
  const int ar0 = c0 >> 2, ak0 = (c0 & 3) * 8;
  const int ar1 = c1 >> 2, ak1 = (c1 & 3) * 8;
  const uint16_t* a0 = Ag + (size_t)(rowBase + ar0) * lda + ak0;
  const uint16_t* a1 = Ag + (size_t)(rowBase + ar1) * lda + ak1;
  const uint16_t* b0 = Bg + (size_t)(colBase + ar0) * ldb + ak0;
  const uint16_t* b1 = Bg + (size_t)(colBase + ar1) * ldb + ak1;

  const int nK = K >> 5;
  for (int kt = 0; kt < nK; ++kt) {
    async16(&As[c0 * 8], a0);
    async16(&As[c1 * 8], a1);
    async16(&Bs[c0 * 8], b0);
    async16(&Bs[c1 * 8], b1);
    a0 += 32; a1 += 32; b0 += 32; b1 += 32;
    __syncthreads();
    f16x8 af[4], bfr[4];
#pragma unroll
    for (int m = 0; m < 4; ++m)
      af[m] = *(const f16x8*)&As[(wr * 64 + m * 16 + l15) * 32 + l4 * 8];
#pragma unroll
    for (int n = 0; n < 4; ++n)
      bfr[n] = *(const f16x8*)&Bs[(wc * 64 + n * 16 + l15) * 32 + l4 * 8];
#pragma unroll
    for (int m = 0; m < 4; ++m)
#pragma unroll
      for (int n = 0; n < 4; ++n)
        acc[m][n] = __builtin_amdgcn_mfma_f32_16x16x32_f16(af[m], bfr[n], acc[m][n], 0, 0, 0);
    __syncthreads();
  }

  const int orow = rowBase + wr * 64 + l4 * 4;
  const int ocol = colBase + wc * 64 + l15;
  if (EPI == 2) {
    // acc = (8x)@Wv = 8*v_pre; s = acc/8 + bias
    uint16_t* C = (uint16_t*)Cv;
#pragma unroll
    for (int n = 0; n < 4; ++n) {
      const float bv = bias[ocol + n * 16];
#pragma unroll
      for (int m = 0; m < 4; ++m)
#pragma unroll
        for (int j = 0; j < 4; ++j)
          C[(size_t)(orow + m * 16 + j) * ldc + ocol + n * 16] =
              f2h_u(acc[m][n][j] * 0.125f + bv);
    }
  } else if (EPI == 3) {
    uint16_t* C = (uint16_t*)Cv + (size_t)blockIdx.z * strC;
#pragma unroll
    for (int n = 0; n < 4; ++n)
#pragma unroll
      for (int m = 0; m < 4; ++m)
#pragma unroll
        for (int j = 0; j < 4; ++j)
          C[(size_t)(orow + m * 16 + j) * ldc + ocol + n * 16] = f2h_u(acc[m][n][j]);
  } else {
    float* C = (float*)Cv;
#pragma unroll
    for (int n = 0; n < 4; ++n) {
      const float bv = bias[ocol + n * 16];
#pragma unroll
      for (int m = 0; m < 4; ++m)
#pragma unroll
        for (int j = 0; j < 4; ++j)
          C[(size_t)(orow + m * 16 + j) * ldc + ocol + n * 16] = acc[m][n][j] + bv;
    }
  }
}

// ---- row softmax over fp16 logits -> fp16 probs, in place ----
__global__ __launch_bounds__(256)
void softmax_rows(uint16_t* __restrict__ P) {
  const size_t row = blockIdx.x;
  uint16_t* p = P + row * 2048;
  const int tid = threadIdx.x;
  uint4 raw = *(const uint4*)(p + tid * 8);
  uint32_t w[4] = {raw.x, raw.y, raw.z, raw.w};
  float v[8];
#pragma unroll
  for (int q = 0; q < 4; ++q) {
    __half2 h = *(__half2*)&w[q];
    float2 f = __half22float2(h);
    v[2 * q] = f.x;
    v[2 * q + 1] = f.y;
  }
  float mx = v[0];
#pragma unroll
  for (int j = 1; j < 8; ++j) mx = fmaxf(mx, v[j]);
#pragma unroll
  for (int o = 32; o > 0; o >>= 1) mx = fmaxf(mx, __shfl_xor(mx, o));
  __shared__ float redm[4], reds[4];
  if ((tid & 63) == 0) redm[tid >> 6] = mx;
  __syncthreads();
  mx = fmaxf(fmaxf(redm[0], redm[1]), fmaxf(redm[2], redm[3]));
  float e[8];
  float se = 0.f;
#pragma unroll
  for (int j = 0; j < 8; ++j) { e[j] = __expf(v[j] - mx); se += e[j]; }
#pragma unroll
  for (int o = 32; o > 0; o >>= 1) se += __shfl_xor(se, o);
  if ((tid & 63) == 0) reds[tid >> 6] = se;
  __syncthreads();
  se = (reds[0] + reds[1]) + (reds[2] + reds[3]);
  const float inv = 1.0f / se;
  uint32_t wo[4];
#pragma unroll
  for (int q = 0; q < 4; ++q) {
    uint16_t a = f2h_u(e[2 * q] * inv);
    uint16_t b = f2h_u(e[2 * q + 1] * inv);
    wo[q] = (uint32_t)a | ((uint32_t)b << 16);
  }
  uint4 ov;
  ov.x = wo[0]; ov.y = wo[1]; ov.z = wo[2]; ov.w = wo[3];
  *(uint4*)(p + tid * 8) = ov;
}

extern "C" void kernel_launch(void* const* d_in, const int* in_sizes, int n_in,
                              void* d_out, int out_size, void* d_ws, size_t ws_size,
                              hipStream_t stream) {
  const float* x     = (const float*)d_in[0];
  const float* Wqkv  = (const float*)d_in[1];
  const float* bqkv  = (const float*)d_in[2];
  const float* Wproj = (const float*)d_in[3];
  const float* bproj = (const float*)d_in[4];
  float* out = (float*)d_out;

  char* ws = (char*)d_ws;
  size_t off = 0;
  auto alloc = [&](size_t bytes) -> void* {
    void* p = ws + off;
    off += (bytes + 255) & ~(size_t)255;
    return p;
  };
  uint16_t* xsplit = (uint16_t*)alloc(8192ULL * 2048 * 2);   // [8192][hi|lo] of 8x
  uint16_t* Wsp    = (uint16_t*)alloc(2048ULL * 2048 * 2);   // [n][hi|lo] of 128*Wqk
  uint16_t* WvT    = (uint16_t*)alloc(1024ULL * 1024 * 2);   // Wv^T fp16
  uint16_t* WpT    = (uint16_t*)alloc(1024ULL * 1024 * 2);   // Wproj^T fp16
  uint16_t* qsp    = (uint16_t*)alloc(4ULL * 2048 * 2048 * 2);  // q splits (8q hi|lo)
  uint16_t* ksp    = (uint16_t*)alloc(4ULL * 2048 * 2048 * 2);  // k splits
  uint16_t* vtmp   = (uint16_t*)alloc(8192ULL * 1024 * 2);   // v fp16 [b t][d]
  uint16_t* vT     = (uint16_t*)alloc(4ULL * 1024 * 2048 * 2);  // v^T fp16 [b][d][t]
  uint16_t* Pm     = (uint16_t*)alloc(4ULL * 2048 * 2048 * 2);  // logits/probs fp16
  uint16_t* ao     = xsplit;  // attn-out fp16 reuses xsplit (dead after v GEMM)

  // 1. x -> scaled fp16 split
  split_x<<<8192, 256, 0, stream>>>(x, xsplit, 2097152);
  // 2. weight preps
  wsplit_t<<<dim3(32, 16), 256, 0, stream>>>(Wqkv, Wsp);
  trans_f2h<<<dim3(16, 16), 256, 0, stream>>>(Wqkv + 2048, WvT, 3072, 1024);
  trans_f2h<<<dim3(16, 16), 256, 0, stream>>>(Wproj, WpT, 1024, 1024);
  // 3. q,k = x@Wqk + b (split3, K=3072) -> split fp16 q,k   [256x128 pipelined]
  gemm256<0><<<dim3(32, 16, 1), 512, 147456, stream>>>(
      xsplit, Wsp, qsp, ksp, bqkv, 2048, 2048, 0, 0, 0, 0);
  // 4. v = x@Wv + b (plain, K=1024)
  gemm_f16<2><<<dim3(64, 8, 1), 256, 0, stream>>>(
      xsplit, WvT, vtmp, bqkv + 2048, 1024, 2048, 1024, 1024, 0, 0, 0);
  // 5. v -> vT per batch
  trans_16<<<dim3(16, 32, 4), 256, 0, stream>>>(vtmp, vT, 1024, 2048, 2097152LL, 2097152LL);
  // 6. logits = sps(q@k^T * scale) (split3, K=3072) -> fp16  [256x128 pipelined]
  gemm256<1><<<dim3(8, 16, 4), 512, 147456, stream>>>(
      qsp, ksp, Pm, nullptr, nullptr, 2048, 2048, 2048,
      4194304LL, 4194304LL, 4194304LL);
  // 7. softmax rows in place
  softmax_rows<<<8192, 256, 0, stream>>>(Pm);
  // 8. attn_out = P@V (K=2048)
  gemm_f16<3><<<dim3(16, 8, 4), 256, 0, stream>>>(
      Pm, vT, ao, nullptr, 2048, 2048, 2048, 1024,
      4194304LL, 2097152LL, 2097152LL);
  // 9. out = ao@Wproj + b -> fp32
  gemm_f16<4><<<dim3(64, 8, 1), 256, 0, stream>>>(
      ao, WpT, out, bproj, 1024, 1024, 1024, 1024, 0, 0, 0);
}

// Round 5
// 229.894 us; speedup vs baseline: 2.1817x; 1.8457x over previous
//
#include <hip/hip_runtime.h>
#include <hip/hip_bf16.h>
#include <hip/hip_fp16.h>
#include <stdint.h>

typedef __attribute__((ext_vector_type(8))) _Float16 f16x8;
typedef __attribute__((ext_vector_type(4))) float f32x4;

__device__ __forceinline__ void async16(void* lds, const void* g) {
  __builtin_amdgcn_global_load_lds(
      (const __attribute__((address_space(1))) void*)g,
      (__attribute__((address_space(3))) void*)lds, 16, 0, 0);
}

__device__ __forceinline__ uint16_t f2h_u(float f) {
  union { __half h; uint16_t u; } c;
  c.h = __float2half(f);  // v_cvt_f16_f32, RNE
  return c.u;
}

// ---- x fp32 -> fp16 [8192][1024] ----
__global__ __launch_bounds__(256)
void conv_f2h(const float* __restrict__ in, uint16_t* __restrict__ out, int n4) {
  int i = blockIdx.x * 256 + threadIdx.x;
  if (i >= n4) return;
  float4 v = ((const float4*)in)[i];
  ushort4 o;
  o.x = f2h_u(v.x); o.y = f2h_u(v.y); o.z = f2h_u(v.z); o.w = f2h_u(v.w);
  ((ushort4*)out)[i] = o;
}

// ---- fp32 [R][C] -> fp16 [C][R] transpose ----
__global__ __launch_bounds__(256)
void trans_f2h(const float* __restrict__ in, uint16_t* __restrict__ out,
               int ldin, int ldout) {
  __shared__ float t[64][65];
  const int tx = threadIdx.x & 63, ty = threadIdx.x >> 6;
  const int r0 = blockIdx.y * 64, c0 = blockIdx.x * 64;
#pragma unroll
  for (int i = 0; i < 16; ++i)
    t[ty + i * 4][tx] = in[(size_t)(r0 + ty + i * 4) * ldin + c0 + tx];
  __syncthreads();
#pragma unroll
  for (int i = 0; i < 16; ++i)
    out[(size_t)(c0 + ty + i * 4) * ldout + r0 + tx] = f2h_u(t[tx][ty + i * 4]);
}

// ================= f16 NT GEMM: 256x128 tile, BK=64, ring-3 LDS, 8 waves =================
// C = A[M,K]*B[N,K]^T (K = nT*64)
// EPI: 0 = qk writer (+bias, split cols to q/k) ; 1 = sps->fp16 ; 2 = vT writer (+bias[row])
//      3 = plain->fp16 ; 4 = +bias->fp32
template <int EPI>
__global__ __launch_bounds__(512, 2)
void gemm256(const uint16_t* __restrict__ A, const uint16_t* __restrict__ B,
             void* __restrict__ Cv, void* __restrict__ Cv2,
             const float* __restrict__ bias,
             int nT, int lda, int ldb, int ldc,
             long long strA, long long strB, long long strC) {
  extern __shared__ uint16_t lds_u16[];  // 3 slots x (A 256x64 + B 128x64) fp16 = 144 KB

  // bijective XCD swizzle on flat block id (all grids have nwg % 8 == 0)
  const int gx = gridDim.x, gy = gridDim.y;
  const int nwg = gx * gy * gridDim.z;
  const int fid = blockIdx.x + gx * (blockIdx.y + gy * blockIdx.z);
  const int fs = (fid & 7) * (nwg >> 3) + (fid >> 3);
  const int bx = fs % gx;
  const int by = (fs / gx) % gy;
  const int bz = fs / (gx * gy);

  const int tid = threadIdx.x;
  const int l = tid & 63;
  const int w = tid >> 6;
  const int wm = w >> 1, wn = w & 1;
  const int l15 = l & 15, l4 = l >> 4;
  const int rowBase = bx * 256, colBase = by * 128;
  const uint16_t* Ag = A + (size_t)bz * strA;
  const uint16_t* Bg = B + (size_t)bz * strB;

  // staging source pointers: linear LDS dest chunk c <- global chunk c^((c>>3)&7)
  const uint16_t* pA[4];
  const uint16_t* pB[2];
#pragma unroll
  for (int u = 0; u < 4; ++u) {
    int c = tid + (u << 9);
    int cs = c ^ ((c >> 3) & 7);
    pA[u] = Ag + (size_t)(rowBase + (cs >> 3)) * lda + (cs & 7) * 8;
  }
#pragma unroll
  for (int u = 0; u < 2; ++u) {
    int c = tid + (u << 9);
    int cs = c ^ ((c >> 3) & 7);
    pB[u] = Bg + (size_t)(colBase + (cs >> 3)) * ldb + (cs & 7) * 8;
  }

  f32x4 acc[4][4];
#pragma unroll
  for (int m = 0; m < 4; ++m)
#pragma unroll
    for (int n = 0; n < 4; ++n)
      acc[m][n] = (f32x4){0.f, 0.f, 0.f, 0.f};

#define STAGE(t2, s2)                                                          \
  {                                                                            \
    const int kb_ = (t2) << 6;                                                 \
    uint16_t* dA_ = lds_u16 + (s2) * 24576;                                    \
    uint16_t* dB_ = dA_ + 16384;                                               \
    _Pragma("unroll") for (int u = 0; u < 4; ++u)                              \
        async16(&dA_[(size_t)(tid + (u << 9)) * 8], pA[u] + kb_);              \
    _Pragma("unroll") for (int u = 0; u < 2; ++u)                              \
        async16(&dB_[(size_t)(tid + (u << 9)) * 8], pB[u] + kb_);              \
  }

  // prologue: tiles 0 and 1 in flight; wait for tile 0 (6 loads of tile 1 remain)
  STAGE(0, 0)
  STAGE(1, 1)
  asm volatile("s_waitcnt vmcnt(6)" ::: "memory");
  __builtin_amdgcn_s_barrier();

  int sl = 0;
  for (int t = 0; t < nT; ++t) {
    int s2 = sl + 2; if (s2 >= 3) s2 -= 3;
    if (t + 2 < nT) STAGE(t + 2, s2)
    const uint16_t* As = lds_u16 + sl * 24576;
    const uint16_t* Bs = As + 16384;
#pragma unroll
    for (int ks = 0; ks < 2; ++ks) {
      f16x8 af[4], bf[4];
#pragma unroll
      for (int m = 0; m < 4; ++m) {
        const int r = wm * 64 + m * 16 + l15;
        const int byt = r * 128 + ((ks * 64 + l4 * 16) ^ ((r & 7) << 4));
        af[m] = *(const f16x8*)((const char*)As + byt);
      }
#pragma unroll
      for (int n = 0; n < 4; ++n) {
        const int r = wn * 64 + n * 16 + l15;
        const int byt = r * 128 + ((ks * 64 + l4 * 16) ^ ((r & 7) << 4));
        bf[n] = *(const f16x8*)((const char*)Bs + byt);
      }
      __builtin_amdgcn_s_setprio(1);
#pragma unroll
      for (int m = 0; m < 4; ++m)
#pragma unroll
        for (int n = 0; n < 4; ++n)
          acc[m][n] = __builtin_amdgcn_mfma_f32_16x16x32_f16(af[m], bf[n], acc[m][n], 0, 0, 0);
      __builtin_amdgcn_s_setprio(0);
    }
    if (t + 1 < nT) {
      if (t + 2 < nT) {
        asm volatile("s_waitcnt vmcnt(6)" ::: "memory");  // tile t+1 landed; t+2 in flight
      } else {
        asm volatile("s_waitcnt vmcnt(0)" ::: "memory");
      }
      __builtin_amdgcn_s_barrier();
    }
    sl = (sl == 2) ? 0 : sl + 1;
  }
#undef STAGE

  const int orow0 = rowBase + wm * 64 + l4 * 4;
  const int ocol0 = colBase + wn * 64 + l15;
  if (EPI == 0) {
    // qkv-qk: A rows = (b,t), cols = q(0..1023)|k(1024..2047); write fp16 q/k per batch
    uint16_t* qd = (uint16_t*)Cv;
    uint16_t* kd = (uint16_t*)Cv2;
#pragma unroll
    for (int n = 0; n < 4; ++n) {
      const int gcol = ocol0 + n * 16;
      const float bv = bias[gcol];
      uint16_t* base = (gcol < 1024 ? qd : kd) + (gcol & 1023);
#pragma unroll
      for (int m = 0; m < 4; ++m)
#pragma unroll
        for (int j = 0; j < 4; ++j) {
          const int grow = orow0 + m * 16 + j;
          base[(size_t)(grow >> 11) * 2097152 + (size_t)(grow & 2047) * 1024] =
              f2h_u(acc[m][n][j] + bv);
        }
    }
  } else if (EPI == 1) {
    // logits: xs = (q.k)*0.125 ; sps bands in logit space
    uint16_t* C = (uint16_t*)Cv + (size_t)bz * strC;
#pragma unroll
    for (int n = 0; n < 4; ++n)
#pragma unroll
      for (int m = 0; m < 4; ++m)
#pragma unroll
        for (int j = 0; j < 4; ++j) {
          float xs = acc[m][n][j] * 0.125f;
          float mult = (xs > 2.94443897916644f) ? 2.0f
                     : (xs > 1.73460105538811f) ? 1.5f
                     : (xs < -2.19722457733622f) ? 0.1f
                     : (xs < -1.09861228866811f) ? 0.3f
                                                 : 1.0f;
          C[(size_t)(orow0 + m * 16 + j) * ldc + ocol0 + n * 16] = f2h_u(xs * mult);
        }
  } else if (EPI == 2) {
    // vT: C[d][t] = acc + bias[d] (bias indexed by ROW)
    uint16_t* C = (uint16_t*)Cv + (size_t)bz * strC;
#pragma unroll
    for (int m = 0; m < 4; ++m)
#pragma unroll
      for (int j = 0; j < 4; ++j) {
        const int d = orow0 + m * 16 + j;
        const float bv = bias[d];
#pragma unroll
        for (int n = 0; n < 4; ++n)
          C[(size_t)d * ldc + ocol0 + n * 16] = f2h_u(acc[m][n][j] + bv);
      }
  } else if (EPI == 3) {
    uint16_t* C = (uint16_t*)Cv + (size_t)bz * strC;
#pragma unroll
    for (int n = 0; n < 4; ++n)
#pragma unroll
      for (int m = 0; m < 4; ++m)
#pragma unroll
        for (int j = 0; j < 4; ++j)
          C[(size_t)(orow0 + m * 16 + j) * ldc + ocol0 + n * 16] = f2h_u(acc[m][n][j]);
  } else {
    float* C = (float*)Cv;
#pragma unroll
    for (int n = 0; n < 4; ++n) {
      const float bv = bias[ocol0 + n * 16];
#pragma unroll
      for (int m = 0; m < 4; ++m)
#pragma unroll
        for (int j = 0; j < 4; ++j)
          C[(size_t)(orow0 + m * 16 + j) * ldc + ocol0 + n * 16] = acc[m][n][j] + bv;
    }
  }
}

// ---- row softmax over fp16 logits -> fp16 probs, in place ----
__global__ __launch_bounds__(256)
void softmax_rows(uint16_t* __restrict__ P) {
  const size_t row = blockIdx.x;
  uint16_t* p = P + row * 2048;
  const int tid = threadIdx.x;
  uint4 raw = *(const uint4*)(p + tid * 8);
  uint32_t w[4] = {raw.x, raw.y, raw.z, raw.w};
  float v[8];
#pragma unroll
  for (int q = 0; q < 4; ++q) {
    __half2 h = *(__half2*)&w[q];
    float2 f = __half22float2(h);
    v[2 * q] = f.x;
    v[2 * q + 1] = f.y;
  }
  float mx = v[0];
#pragma unroll
  for (int j = 1; j < 8; ++j) mx = fmaxf(mx, v[j]);
#pragma unroll
  for (int o = 32; o > 0; o >>= 1) mx = fmaxf(mx, __shfl_xor(mx, o));
  __shared__ float redm[4], reds[4];
  if ((tid & 63) == 0) redm[tid >> 6] = mx;
  __syncthreads();
  mx = fmaxf(fmaxf(redm[0], redm[1]), fmaxf(redm[2], redm[3]));
  float e[8];
  float se = 0.f;
#pragma unroll
  for (int j = 0; j < 8; ++j) { e[j] = __expf(v[j] - mx); se += e[j]; }
#pragma unroll
  for (int o = 32; o > 0; o >>= 1) se += __shfl_xor(se, o);
  if ((tid & 63) == 0) reds[tid >> 6] = se;
  __syncthreads();
  se = (reds[0] + reds[1]) + (reds[2] + reds[3]);
  const float inv = 1.0f / se;
  uint32_t wo[4];
#pragma unroll
  for (int q = 0; q < 4; ++q) {
    uint16_t a = f2h_u(e[2 * q] * inv);
    uint16_t b = f2h_u(e[2 * q + 1] * inv);
    wo[q] = (uint32_t)a | ((uint32_t)b << 16);
  }
  uint4 ov;
  ov.x = wo[0]; ov.y = wo[1]; ov.z = wo[2]; ov.w = wo[3];
  *(uint4*)(p + tid * 8) = ov;
}

extern "C" void kernel_launch(void* const* d_in, const int* in_sizes, int n_in,
                              void* d_out, int out_size, void* d_ws, size_t ws_size,
                              hipStream_t stream) {
  const float* x     = (const float*)d_in[0];
  const float* Wqkv  = (const float*)d_in[1];
  const float* bqkv  = (const float*)d_in[2];
  const float* Wproj = (const float*)d_in[3];
  const float* bproj = (const float*)d_in[4];
  float* out = (float*)d_out;

  char* ws = (char*)d_ws;
  size_t off = 0;
  auto alloc = [&](size_t bytes) -> void* {
    void* p = ws + off;
    off += (bytes + 255) & ~(size_t)255;
    return p;
  };
  uint16_t* xh    = (uint16_t*)alloc(8192ULL * 1024 * 2);      // x fp16 [8192][1024]
  uint16_t* WqkT  = (uint16_t*)alloc(2048ULL * 1024 * 2);      // Wqk^T fp16 [2048][1024]
  uint16_t* WvT   = (uint16_t*)alloc(1024ULL * 1024 * 2);      // Wv^T fp16
  uint16_t* WpT   = (uint16_t*)alloc(1024ULL * 1024 * 2);      // Wproj^T fp16
  uint16_t* qh    = (uint16_t*)alloc(4ULL * 2048 * 1024 * 2);  // q fp16 [b][t][d]
  uint16_t* kh    = (uint16_t*)alloc(4ULL * 2048 * 1024 * 2);  // k fp16 [b][t][d]
  uint16_t* vT    = (uint16_t*)alloc(4ULL * 1024 * 2048 * 2);  // v^T fp16 [b][d][t]
  uint16_t* Pm    = (uint16_t*)alloc(4ULL * 2048 * 2048 * 2);  // logits/probs fp16
  uint16_t* ao    = xh;  // attn-out fp16 reuses xh (x dead after qk & v GEMMs)

  // 1. x -> fp16
  conv_f2h<<<8192, 256, 0, stream>>>(x, xh, 2097152);
  // 2. weight transposes -> fp16
  trans_f2h<<<dim3(32, 16), 256, 0, stream>>>(Wqkv, WqkT, 3072, 1024);          // q|k cols
  trans_f2h<<<dim3(16, 16), 256, 0, stream>>>(Wqkv + 2048, WvT, 3072, 1024);    // v cols
  trans_f2h<<<dim3(16, 16), 256, 0, stream>>>(Wproj, WpT, 1024, 1024);
  // 3. q,k = x@Wqk + b   (M=8192, N=2048, K=1024)
  gemm256<0><<<dim3(32, 16, 1), 512, 147456, stream>>>(
      xh, WqkT, qh, kh, bqkv, 16, 1024, 1024, 0, 0, 0, 0);
  // 4. vT[b][d][t] = (Wv^T @ x_b^T) + bias_v[d]  (M=1024, N=2048, K=1024, per batch)
  gemm256<2><<<dim3(4, 16, 4), 512, 147456, stream>>>(
      WvT, xh, vT, nullptr, bqkv + 2048, 16, 1024, 1024, 2048,
      0, 2097152LL, 2097152LL);
  // 5. logits = sps(q@k^T * 0.125)  (M=N=2048, K=1024, per batch)
  gemm256<1><<<dim3(8, 16, 4), 512, 147456, stream>>>(
      qh, kh, Pm, nullptr, nullptr, 16, 1024, 1024, 2048,
      2097152LL, 2097152LL, 4194304LL);
  // 6. softmax rows in place
  softmax_rows<<<8192, 256, 0, stream>>>(Pm);
  // 7. attn_out = P@V  (M=2048, N=1024, K=2048, per batch)
  gemm256<3><<<dim3(8, 8, 4), 512, 147456, stream>>>(
      Pm, vT, ao, nullptr, nullptr, 32, 2048, 2048, 1024,
      4194304LL, 2097152LL, 2097152LL);
  // 8. out = ao@Wproj + b -> fp32  (M=8192, N=1024, K=1024)
  gemm256<4><<<dim3(32, 8, 1), 512, 147456, stream>>>(
      ao, WpT, out, nullptr, bproj, 16, 1024, 1024, 1024, 0, 0, 0);
}